// Round 7
// baseline (5702.381 us; speedup 1.0000x reference)
//
#include <hip/hip_runtime.h>
#include <hip/hip_bf16.h>
#include <stdint.h>

typedef __hip_bfloat16 bf;

static constexpr int Bb = 4, Sdim = 2048, Ddim = 1024, Hn = 16, HD = 64, Kd = 1024;
static constexpr float NEG = -1e30f;   // finite "minus infinity" — fast-math safe

__device__ __forceinline__ void stc(bf* p, float v)    { *p = __float2bfloat16(v); }
__device__ __forceinline__ void stc(float* p, float v) { *p = v; }

// Dead-simple tiled fp32 GEMM: C = A @ W^T + bias.
// A: M x K fp32, W: N x K fp32 (nn.Linear weight), bias fp32, C bf16 or fp32.
// 64x64 tile, BK=16, 256 threads x (4x4 each). No MFMA, no async, no tricks.
template<typename TC, bool HEADLAYOUT>
__global__ __launch_bounds__(256)
void ngemm(const float* __restrict__ A,
           const float* __restrict__ W0, const float* __restrict__ W1, const float* __restrict__ W2,
           const float* __restrict__ b0, const float* __restrict__ b1, const float* __restrict__ b2,
           TC* __restrict__ C0, TC* __restrict__ C1, TC* __restrict__ C2)
{
  const int z = blockIdx.z;
  const float* W    = z == 0 ? W0 : (z == 1 ? W1 : W2);
  const float* bias = z == 0 ? b0 : (z == 1 ? b1 : b2);
  TC*          C    = z == 0 ? C0 : (z == 1 ? C1 : C2);

  __shared__ float As[64][17];   // [m][k], +1 pad
  __shared__ float Bs[64][17];   // [n][k], +1 pad

  const int tid = threadIdx.x;
  const int tx = tid & 15, ty = tid >> 4;
  const int m0 = blockIdx.x * 64, n0 = blockIdx.y * 64;
  const int sr = tid >> 2, sc = (tid & 3) * 4;   // staging: 64 rows x 16 cols, 4/thread

  float acc[4][4] = {};

  for (int kt = 0; kt < Kd; kt += 16) {
#pragma unroll
    for (int j = 0; j < 4; ++j) {
      As[sr][sc + j] = A[(int64_t)(m0 + sr) * Kd + kt + sc + j];
      Bs[sr][sc + j] = W[(int64_t)(n0 + sr) * Kd + kt + sc + j];
    }
    __syncthreads();
#pragma unroll
    for (int kk = 0; kk < 16; ++kk) {
      float a[4], b[4];
#pragma unroll
      for (int i = 0; i < 4; ++i) a[i] = As[ty * 4 + i][kk];
#pragma unroll
      for (int j = 0; j < 4; ++j) b[j] = Bs[tx * 4 + j][kk];
#pragma unroll
      for (int i = 0; i < 4; ++i)
#pragma unroll
        for (int j = 0; j < 4; ++j) acc[i][j] += a[i] * b[j];
    }
    __syncthreads();
  }

#pragma unroll
  for (int i = 0; i < 4; ++i) {
    const int gm = m0 + ty * 4 + i;
#pragma unroll
    for (int j = 0; j < 4; ++j) {
      const int gn = n0 + tx * 4 + j;
      const float v = acc[i][j] + bias[gn];
      if (HEADLAYOUT) {
        const int bidx = gm >> 11, s = gm & (Sdim - 1);
        const int h = gn >> 6, hd = gn & (HD - 1);
        stc(&C[(((int64_t)(bidx * Hn + h) * Sdim + s) << 6) + hd], v);
      } else {
        stc(&C[(int64_t)gm * Ddim + gn], v);
      }
    }
  }
}

// Naive fp32 flash attention. Workgroup = 256 threads: one (b,h), 32 q-rows.
// Thread (tq=tid>>3, oc=tid&7) owns O[hd = oc*8 .. +7] for q-row tq.
// Output ao is FP32 now (precision + dtype-correct final stage).
__global__ __launch_bounds__(256)
void attn_naive(const bf* __restrict__ qh, const bf* __restrict__ kh,
                const bf* __restrict__ vh, const int* __restrict__ mask,
                float* __restrict__ outp)
{
  __shared__ float Qs[32][65];
  __shared__ float Ks[64][65];
  __shared__ float Vs[64][65];
  __shared__ float Ps[32][65];
  __shared__ float rowm[32], rowl[32], rowa[32];

  const int tid = threadIdx.x;
  const int bh = blockIdx.x;          // b*16 + h
  const int b = bh >> 4, h = bh & 15;
  const int q0 = blockIdx.y * 32;
  const int64_t base = (int64_t)bh * Sdim * HD;

  const int tq = tid >> 3;            // 0..31
  const int oc = tid & 7;             // 0..7

  for (int j = 0; j < 8; ++j)
    Qs[tq][oc * 8 + j] = __bfloat162float(qh[base + (q0 + tq) * 64 + oc * 8 + j]);
  if (tid < 32) { rowm[tid] = NEG; rowl[tid] = 0.f; }
  __syncthreads();

  float O[8] = {};
  const bool qlive = mask[b * Sdim + q0 + tq] != 0;

  for (int kt = 0; kt < Sdim; kt += 64) {
    {   // stage K/V tile (64x64) bf16 -> fp32
      const int kr = tid >> 2;
      const int c0 = (tid & 3) * 16;
      for (int j = 0; j < 16; ++j) {
        Ks[kr][c0 + j] = __bfloat162float(kh[base + (kt + kr) * 64 + c0 + j]);
        Vs[kr][c0 + j] = __bfloat162float(vh[base + (kt + kr) * 64 + c0 + j]);
      }
    }
    __syncthreads();

    for (int kk = 0; kk < 8; ++kk) {
      const int k = oc * 8 + kk;
      const bool klive = mask[b * Sdim + kt + k] != 0;
      float s = NEG;
      if (klive && qlive) {
        s = 0.f;
        for (int d = 0; d < 64; ++d) s += Qs[tq][d] * Ks[k][d];
        s *= 0.125f;
      }
      Ps[tq][k] = s;
    }
    __syncthreads();

    if (tid < 32) {
      const float mo = rowm[tid];
      float mx = mo;
      for (int k = 0; k < 64; ++k) mx = fmaxf(mx, Ps[tid][k]);
      const float al = __expf(mo - mx);
      float sum = 0.f;
      for (int k = 0; k < 64; ++k) {
        const float p = __expf(Ps[tid][k] - mx);
        Ps[tid][k] = p;
        sum += p;
      }
      rowm[tid] = mx;
      rowl[tid] = rowl[tid] * al + sum;
      rowa[tid] = al;
    }
    __syncthreads();

    const float al = rowa[tq];
    for (int j = 0; j < 8; ++j) O[j] *= al;
    for (int k = 0; k < 64; ++k) {
      const float p = Ps[tq][k];
      for (int j = 0; j < 8; ++j) O[j] += p * Vs[k][oc * 8 + j];
    }
    __syncthreads();
  }

  const float linv = qlive ? 1.f / rowl[tq] : 0.f;   // masked rows -> exact 0
  for (int j = 0; j < 8; ++j)
    outp[((int64_t)b * Sdim + q0 + tq) * Ddim + h * 64 + oc * 8 + j] = O[j] * linv;
}

extern "C" void kernel_launch(void* const* d_in, const int* in_sizes, int n_in,
                              void* d_out, int out_size, void* d_ws, size_t ws_size,
                              hipStream_t stream) {
  (void)in_sizes; (void)n_in; (void)out_size; (void)ws_size;
  const float* q    = (const float*)d_in[0];
  const int*   mask = (const int*)d_in[1];
  const float* Wq   = (const float*)d_in[2];
  const float* bq   = (const float*)d_in[3];
  const float* Wk   = (const float*)d_in[4];
  const float* bk   = (const float*)d_in[5];
  const float* Wv   = (const float*)d_in[6];
  const float* bv   = (const float*)d_in[7];
  const float* Wo   = (const float*)d_in[8];
  const float* bo   = (const float*)d_in[9];
  float* out = (float*)d_out;                 // reference output dtype: FP32
  bf* ws  = (bf*)d_ws;

  constexpr size_t SZ = (size_t)Bb * Sdim * Ddim;   // 8,388,608 elems
  bf* qhp = ws;                                     // bf16, 16.8 MB
  bf* khp = ws + SZ;
  bf* vhp = ws + 2 * SZ;
  float* ao = (float*)(ws + 3 * SZ);                // fp32, 33.6 MB (total ws: 84 MB)

  // QKV projections (fp32 direct) -> head layout (b,h,s,hd) bf16
  ngemm<bf, true><<<dim3(128, 16, 3), dim3(256), 0, stream>>>(
      q, Wq, Wk, Wv, bq, bk, bv, qhp, khp, vhp);

  // Attention -> (b,s,d) fp32
  attn_naive<<<dim3(Bb * Hn, Sdim / 32), dim3(256), 0, stream>>>(qhp, khp, vhp, mask, ao);

  // Output projection -> d_out (fp32)
  ngemm<float, false><<<dim3(128, 16, 1), dim3(256), 0, stream>>>(
      ao, Wo, Wo, Wo, bo, bo, bo, out, out, out);
}

// Round 8
// 606.057 us; speedup vs baseline: 9.4090x; 9.4090x over previous
//
#include <hip/hip_runtime.h>
#include <hip/hip_bf16.h>
#include <stdint.h>

typedef __bf16 v8y __attribute__((ext_vector_type(8)));
typedef float  v4f __attribute__((ext_vector_type(4)));
typedef __hip_bfloat16 bf;

#define AS1 __attribute__((address_space(1)))
#define AS3 __attribute__((address_space(3)))

__device__ __forceinline__ void gload16(const bf* g, bf* l) {
  __builtin_amdgcn_global_load_lds((const AS1 uint32_t*)g, (AS3 uint32_t*)l, 16, 0, 0);
}

static constexpr int Bb = 4, Sdim = 2048, Ddim = 1024, Hn = 16, HD = 64;
static constexpr int Kd = 1024, Nd = 1024;
static constexpr float NEG = -1e30f;   // finite "minus infinity" — fast-math safe

__device__ __forceinline__ void stc(bf* p, float v)    { *p = __float2bfloat16(v); }
__device__ __forceinline__ void stc(float* p, float v) { *p = v; }

// fp32 -> bf16 hi/lo split (lo captures rounding residual; lo==nullptr skips it).
__global__ __launch_bounds__(256)
void cvt_split(const float* __restrict__ src, bf* __restrict__ hi, bf* __restrict__ lo, int n) {
  const int i = (blockIdx.x * 256 + threadIdx.x) * 8;
  if (i >= n) return;
  const float4 a = *reinterpret_cast<const float4*>(src + i);
  const float4 b = *reinterpret_cast<const float4*>(src + i + 4);
  const float x[8] = {a.x, a.y, a.z, a.w, b.x, b.y, b.z, b.w};
  union { bf h[8]; uint4 u; } H, L;
#pragma unroll
  for (int j = 0; j < 8; ++j) {
    const bf h = __float2bfloat16(x[j]);
    H.h[j] = h;
    L.h[j] = __float2bfloat16(x[j] - __bfloat162float(h));
  }
  *reinterpret_cast<uint4*>(hi + i) = H.u;
  if (lo) *reinterpret_cast<uint4*>(lo + i) = L.u;
}

// C = A @ W^T + bias.  128x128 tile, BK=32, 4 waves, 4x4 grid of 16x16x32 MFMAs.
// SPLIT: acc = AhWh + AhWl + AlWh (fp32-grade inputs).  TC = bf16 or fp32 store.
template<bool SPLIT, bool HEADLAYOUT, typename TC>
__global__ __launch_bounds__(256)
void gemm_bt(const bf* __restrict__ Ah, const bf* __restrict__ Al,
             const bf* __restrict__ W0h, const bf* __restrict__ W0l,
             const bf* __restrict__ W1h, const bf* __restrict__ W1l,
             const bf* __restrict__ W2h, const bf* __restrict__ W2l,
             const float* __restrict__ b0, const float* __restrict__ b1, const float* __restrict__ b2,
             TC* __restrict__ C0, TC* __restrict__ C1, TC* __restrict__ C2)
{
  const int z = blockIdx.z;
  const bf* Wh = z == 0 ? W0h : (z == 1 ? W1h : W2h);
  const bf* Wl = z == 0 ? W0l : (z == 1 ? W1l : W2l);
  const float* bias = z == 0 ? b0 : (z == 1 ? b1 : b2);
  TC* C = z == 0 ? C0 : (z == 1 ? C1 : C2);

  constexpr int PL = 128 * 32;
  __shared__ __align__(16) bf As[(SPLIT ? 2 : 1) * PL];
  __shared__ __align__(16) bf Bs[(SPLIT ? 2 : 1) * PL];

  const int tid = threadIdx.x;
  const int w = tid >> 6, l = tid & 63;
  const int m0 = blockIdx.x * 128, n0 = blockIdx.y * 128;
  const int wm = (w & 1) * 64, wn = (w >> 1) * 64;
  const int lr = l & 15, quad = l >> 4;
  const int srow = l >> 2, sk = (l & 3) * 8;

  v4f acc[4][4] = {};

  for (int kt = 0; kt < Kd; kt += 32) {
    __syncthreads();
#pragma unroll
    for (int c = 0; c < 2; ++c) {
      const int rb = (c * 4 + w) * 16;   // wave-uniform 16-row chunk (1 KiB)
      const int64_t goff = (int64_t)(rb + srow) * Kd + kt + sk;
      gload16(Ah + (int64_t)m0 * Kd + goff, As + rb * 32);
      gload16(Wh + (int64_t)n0 * Kd + goff, Bs + rb * 32);
      if (SPLIT) {
        gload16(Al + (int64_t)m0 * Kd + goff, As + PL + rb * 32);
        gload16(Wl + (int64_t)n0 * Kd + goff, Bs + PL + rb * 32);
      }
    }
    __syncthreads();

    v8y afh[4], bfh[4], afl[4], bfl[4];
#pragma unroll
    for (int i = 0; i < 4; ++i) {
      const int ro = (wm + i * 16 + lr) * 32 + quad * 8;
      const int co = (wn + i * 16 + lr) * 32 + quad * 8;
      afh[i] = *reinterpret_cast<const v8y*>(As + ro);
      bfh[i] = *reinterpret_cast<const v8y*>(Bs + co);
      if (SPLIT) {
        afl[i] = *reinterpret_cast<const v8y*>(As + PL + ro);
        bfl[i] = *reinterpret_cast<const v8y*>(Bs + PL + co);
      }
    }
#pragma unroll
    for (int i = 0; i < 4; ++i)
#pragma unroll
      for (int j = 0; j < 4; ++j) {
        acc[i][j] = __builtin_amdgcn_mfma_f32_16x16x32_bf16(afh[i], bfh[j], acc[i][j], 0, 0, 0);
        if (SPLIT) {
          acc[i][j] = __builtin_amdgcn_mfma_f32_16x16x32_bf16(afh[i], bfl[j], acc[i][j], 0, 0, 0);
          acc[i][j] = __builtin_amdgcn_mfma_f32_16x16x32_bf16(afl[i], bfh[j], acc[i][j], 0, 0, 0);
        }
      }
  }

  // Epilogue: C/D layout col = lane&15, row = quad*4 + reg (m89-verified).
#pragma unroll
  for (int j = 0; j < 4; ++j) {
    const int gn = n0 + wn + j * 16 + lr;
    const float bv = bias[gn];
#pragma unroll
    for (int i = 0; i < 4; ++i) {
#pragma unroll
      for (int r = 0; r < 4; ++r) {
        const int gm = m0 + wm + i * 16 + quad * 4 + r;
        const float v = acc[i][j][r] + bv;
        if (HEADLAYOUT) {
          const int bidx = gm >> 11, s = gm & (Sdim - 1);
          const int h = gn >> 6, hd = gn & (HD - 1);
          stc(&C[(((int64_t)(bidx * Hn + h) * Sdim + s) << 6) + hd], v);
        } else {
          stc(&C[(int64_t)gm * Nd + gn], v);
        }
      }
    }
  }
}

// MFMA flash attention: one workgroup per (b*h, 64 q rows); each of 4 waves owns 16
// q rows.  qh/kh/vh in (b,h,s,hd) bf16.  Online softmax, finite -1e30 sentinel.
// P: MFMA C-layout -> per-wave LDS -> A-layout.  Output (b,s,h*64+hd) bf16;
// masked q-rows exact 0 (final GEMM bias then reproduces bo).
__global__ __launch_bounds__(256)
void attn_kernel(const bf* __restrict__ qh, const bf* __restrict__ kh,
                 const bf* __restrict__ vh, const int* __restrict__ mask,
                 bf* __restrict__ outp)
{
  __shared__ __align__(16) bf Kt[32 * 72];       // [key][hd], padded stride 72
  __shared__ __align__(16) bf Vt[64 * 40];       // [hd][key], padded stride 40
  __shared__ __align__(16) bf Pb[4][16 * 40];    // per-wave P, [q][key], stride 40

  const int tid = threadIdx.x;
  const int w = tid >> 6, l = tid & 63;
  const int bh = blockIdx.x;
  const int b = bh >> 4;
  const int q0 = blockIdx.y * 64 + w * 16;
  const int lr = l & 15, quad = l >> 4;
  const int64_t base = (int64_t)bh * Sdim * HD;

  v8y qf[2];
#pragma unroll
  for (int ks = 0; ks < 2; ++ks)
    qf[ks] = *reinterpret_cast<const v8y*>(qh + base + (q0 + lr) * 64 + ks * 32 + quad * 8);

  bool qm[4];
#pragma unroll
  for (int r = 0; r < 4; ++r) qm[r] = mask[b * Sdim + q0 + quad * 4 + r] != 0;

  float m_i[4], l_i[4];
#pragma unroll
  for (int r = 0; r < 4; ++r) { m_i[r] = NEG; l_i[r] = 0.f; }
  v4f O[4] = {};

  const int krow = tid >> 3, kc = tid & 7;         // K staging: 32 rows x 8 chunks
  const int vkey = tid & 31, vd0 = (tid >> 5) * 8; // V staging (transpose)

  for (int kt = 0; kt < Sdim; kt += 32) {
    __syncthreads();
    {
      uint4 kv = *reinterpret_cast<const uint4*>(kh + base + (kt + krow) * 64 + kc * 8);
      *reinterpret_cast<uint4*>((char*)Kt + krow * 144 + kc * 16) = kv;
      uint4 vv = *reinterpret_cast<const uint4*>(vh + base + (kt + vkey) * 64 + vd0);
      const bf* ve = reinterpret_cast<const bf*>(&vv);
#pragma unroll
      for (int j = 0; j < 8; ++j) Vt[(vd0 + j) * 40 + vkey] = ve[j];
    }
    __syncthreads();

    // S = Q K^T : two 16-key tiles, two K-steps over hd
    v4f sf[2] = {};
#pragma unroll
    for (int nt = 0; nt < 2; ++nt)
#pragma unroll
      for (int ks = 0; ks < 2; ++ks) {
        v8y kf = *reinterpret_cast<const v8y*>((const char*)Kt + (nt * 16 + lr) * 144 + ks * 64 + quad * 16);
        sf[nt] = __builtin_amdgcn_mfma_f32_16x16x32_bf16(qf[ks], kf, sf[nt], 0, 0, 0);
      }

    bool km[2];
    km[0] = mask[b * Sdim + kt + lr] != 0;
    km[1] = mask[b * Sdim + kt + 16 + lr] != 0;

    float s[2][4], p[2][4];
#pragma unroll
    for (int nt = 0; nt < 2; ++nt)
#pragma unroll
      for (int r = 0; r < 4; ++r)
        s[nt][r] = (km[nt] && qm[r]) ? sf[nt][r] * 0.125f : NEG;

    float mn[4], alpha[4];
#pragma unroll
    for (int r = 0; r < 4; ++r) {
      float v = fmaxf(s[0][r], s[1][r]);
#pragma unroll
      for (int off = 1; off < 16; off <<= 1) v = fmaxf(v, __shfl_xor(v, off));
      mn[r] = fmaxf(m_i[r], v);
      alpha[r] = __expf(m_i[r] - mn[r]);   // finite: exp(0)=1 while empty
      m_i[r] = mn[r];
    }
#pragma unroll
    for (int r = 0; r < 4; ++r) {
      p[0][r] = __expf(s[0][r] - mn[r]);   // masked keys -> exact 0
      p[1][r] = __expf(s[1][r] - mn[r]);
      float v = p[0][r] + p[1][r];
#pragma unroll
      for (int off = 1; off < 16; off <<= 1) v += __shfl_xor(v, off);
      l_i[r] = l_i[r] * alpha[r] + v;
    }
#pragma unroll
    for (int dt = 0; dt < 4; ++dt)
#pragma unroll
      for (int r = 0; r < 4; ++r) O[dt][r] *= alpha[r];

    // P: C-layout -> LDS -> A-layout (per-wave region)
    bf* Pw = Pb[w];
#pragma unroll
    for (int nt = 0; nt < 2; ++nt)
#pragma unroll
      for (int r = 0; r < 4; ++r)
        Pw[(quad * 4 + r) * 40 + nt * 16 + lr] = __float2bfloat16(p[nt][r]);
    __syncthreads();

    v8y pa = *reinterpret_cast<const v8y*>((const char*)Pw + lr * 80 + quad * 16);
#pragma unroll
    for (int dt = 0; dt < 4; ++dt) {
      v8y vf = *reinterpret_cast<const v8y*>((const char*)Vt + (dt * 16 + lr) * 80 + quad * 16);
      O[dt] = __builtin_amdgcn_mfma_f32_16x16x32_bf16(pa, vf, O[dt], 0, 0, 0);
    }
  }

#pragma unroll
  for (int dt = 0; dt < 4; ++dt)
#pragma unroll
    for (int r = 0; r < 4; ++r) {
      const int qrow = q0 + quad * 4 + r;
      const float v = qm[r] ? O[dt][r] / l_i[r] : 0.f;
      outp[((int64_t)b * Sdim + qrow) * Ddim + (bh & 15) * 64 + dt * 16 + lr] = __float2bfloat16(v);
    }
}

extern "C" void kernel_launch(void* const* d_in, const int* in_sizes, int n_in,
                              void* d_out, int out_size, void* d_ws, size_t ws_size,
                              hipStream_t stream) {
  (void)in_sizes; (void)n_in; (void)out_size; (void)ws_size;
  const float* q    = (const float*)d_in[0];
  const int*   mask = (const int*)d_in[1];   // int32 0/1 — verified round 7
  const float* Wq = (const float*)d_in[2];
  const float* bq = (const float*)d_in[3];
  const float* Wk = (const float*)d_in[4];
  const float* bk = (const float*)d_in[5];
  const float* Wv = (const float*)d_in[6];
  const float* bv = (const float*)d_in[7];
  const float* Wo = (const float*)d_in[8];
  const float* bo = (const float*)d_in[9];
  float* out = (float*)d_out;                // fp32 output — verified round 7
  bf* ws  = (bf*)d_ws;

  constexpr int SZ  = Bb * Sdim * Ddim;   // 8,388,608
  constexpr int WSZ = Ddim * Ddim;        // 1,048,576

  bf* qc_h = ws;                 // A hi (reused as attention output `ao` later)
  bf* qc_l = ws + (size_t)SZ;    // A lo
  bf* qhp  = ws + 2 * (size_t)SZ;
  bf* khp  = ws + 3 * (size_t)SZ;
  bf* vhp  = ws + 4 * (size_t)SZ;
  bf* wb   = ws + 5 * (size_t)SZ;
  bf* wq_h = wb;            bf* wq_l = wb + WSZ;
  bf* wk_h = wb + 2 * WSZ;  bf* wk_l = wb + 3 * WSZ;
  bf* wv_h = wb + 4 * WSZ;  bf* wv_l = wb + 5 * WSZ;
  bf* wo_h = wb + 6 * WSZ;
  bf* ao   = qc_h;   // safe: QKV GEMM consumed qc before attn writes ao

  // Prologue: fp32 -> bf16 hi/lo conversions
  cvt_split<<<dim3(SZ / 2048), dim3(256), 0, stream>>>(q,  qc_h, qc_l, SZ);
  cvt_split<<<dim3(WSZ / 2048), dim3(256), 0, stream>>>(Wq, wq_h, wq_l, WSZ);
  cvt_split<<<dim3(WSZ / 2048), dim3(256), 0, stream>>>(Wk, wk_h, wk_l, WSZ);
  cvt_split<<<dim3(WSZ / 2048), dim3(256), 0, stream>>>(Wv, wv_h, wv_l, WSZ);
  cvt_split<<<dim3(WSZ / 2048), dim3(256), 0, stream>>>(Wo, wo_h, nullptr, WSZ);

  // Fused QKV projections (split precision) -> head layout (b,h,s,hd) bf16
  gemm_bt<true, true, bf><<<dim3(64, 8, 3), dim3(256), 0, stream>>>(
      qc_h, qc_l, wq_h, wq_l, wk_h, wk_l, wv_h, wv_l, bq, bk, bv, qhp, khp, vhp);

  // Attention -> (b,s,d) bf16
  attn_kernel<<<dim3(Bb * Hn, Sdim / 64), dim3(256), 0, stream>>>(qhp, khp, vhp, mask, ao);

  // Output projection (single bf16) -> d_out fp32
  gemm_bt<false, false, float><<<dim3(64, 8, 1), dim3(256), 0, stream>>>(
      ao, nullptr, wo_h, nullptr, wo_h, nullptr, wo_h, nullptr, bo, bo, bo, out, out, out);
}

// Round 9
// 514.299 us; speedup vs baseline: 11.0877x; 1.1784x over previous
//
#include <hip/hip_runtime.h>
#include <hip/hip_bf16.h>
#include <stdint.h>

typedef __bf16 v8y __attribute__((ext_vector_type(8)));
typedef float  v4f __attribute__((ext_vector_type(4)));
typedef __hip_bfloat16 bf;

#define AS1 __attribute__((address_space(1)))
#define AS3 __attribute__((address_space(3)))

__device__ __forceinline__ void gload16(const bf* g, bf* l) {
  __builtin_amdgcn_global_load_lds((const AS1 uint32_t*)g, (AS3 uint32_t*)l, 16, 0, 0);
}

static constexpr int Bb = 4, Sdim = 2048, Ddim = 1024, Hn = 16, HD = 64;
static constexpr int Kd = 1024, Nd = 1024;
static constexpr int WSZ = Ddim * Ddim;
static constexpr float NEG = -1e30f;   // finite "minus infinity" — fast-math safe

__device__ __forceinline__ void stc(bf* p, float v)    { *p = __float2bfloat16(v); }
__device__ __forceinline__ void stc(float* p, float v) { *p = v; }

// fp32 -> bf16 hi/lo split.
__device__ __forceinline__ void split8(const float* src, bf* hi, bf* lo, int i) {
  const float4 a = *reinterpret_cast<const float4*>(src + i);
  const float4 b = *reinterpret_cast<const float4*>(src + i + 4);
  const float x[8] = {a.x, a.y, a.z, a.w, b.x, b.y, b.z, b.w};
  union { bf h[8]; uint4 u; } H, L;
#pragma unroll
  for (int j = 0; j < 8; ++j) {
    const bf h = __float2bfloat16(x[j]);
    H.h[j] = h;
    L.h[j] = __float2bfloat16(x[j] - __bfloat162float(h));
  }
  *reinterpret_cast<uint4*>(hi + i) = H.u;
  if (lo) *reinterpret_cast<uint4*>(lo + i) = L.u;
}

__global__ __launch_bounds__(256)
void cvt_split(const float* __restrict__ src, bf* __restrict__ hi, bf* __restrict__ lo, int n) {
  const int i = (blockIdx.x * 256 + threadIdx.x) * 8;
  if (i < n) split8(src, hi, lo, i);
}

// All four weight conversions in one launch; wb layout: [wq_h wq_l wk_h wk_l wv_h wv_l wo_h]
__global__ __launch_bounds__(256)
void cvt_w(const float* __restrict__ Wq, const float* __restrict__ Wk,
           const float* __restrict__ Wv, const float* __restrict__ Wo,
           bf* __restrict__ wb) {
  const int i = (blockIdx.x * 256 + threadIdx.x) * 8;
  const int z = blockIdx.y;
  const float* src = z == 0 ? Wq : (z == 1 ? Wk : (z == 2 ? Wv : Wo));
  bf* hi = wb + (size_t)2 * WSZ * z;              // z==3 -> wb+6*WSZ (wo_h)
  bf* lo = (z == 3) ? nullptr : hi + WSZ;
  split8(src, hi, lo, i);
}

// C = A @ W^T + bias.  128x128 tile, BK=32, 4 waves, 4x4 grid of 16x16x32 MFMAs.
// SPLIT: acc = AhWh + AhWl + AlWh.  HEADLAYOUT: z==0 -> Q (b,h,s,hd) PRE-SCALED by
// 0.125; z==1 -> K (b,h,s,hd); z==2 -> V TRANSPOSED (b,h,hd,s).
template<bool SPLIT, bool HEADLAYOUT, typename TC>
__global__ __launch_bounds__(256)
void gemm_bt(const bf* __restrict__ Ah, const bf* __restrict__ Al,
             const bf* __restrict__ W0h, const bf* __restrict__ W0l,
             const bf* __restrict__ W1h, const bf* __restrict__ W1l,
             const bf* __restrict__ W2h, const bf* __restrict__ W2l,
             const float* __restrict__ b0, const float* __restrict__ b1, const float* __restrict__ b2,
             TC* __restrict__ C0, TC* __restrict__ C1, TC* __restrict__ C2)
{
  const int z = blockIdx.z;
  const bf* Wh = z == 0 ? W0h : (z == 1 ? W1h : W2h);
  const bf* Wl = z == 0 ? W0l : (z == 1 ? W1l : W2l);
  const float* bias = z == 0 ? b0 : (z == 1 ? b1 : b2);
  TC* C = z == 0 ? C0 : (z == 1 ? C1 : C2);

  constexpr int PL = 128 * 32;
  __shared__ __align__(16) bf As[(SPLIT ? 2 : 1) * PL];
  __shared__ __align__(16) bf Bs[(SPLIT ? 2 : 1) * PL];

  const int tid = threadIdx.x;
  const int w = tid >> 6, l = tid & 63;
  const int m0 = blockIdx.x * 128, n0 = blockIdx.y * 128;
  const int wm = (w & 1) * 64, wn = (w >> 1) * 64;
  const int lr = l & 15, quad = l >> 4;
  const int srow = l >> 2, sk = (l & 3) * 8;

  v4f acc[4][4] = {};

  for (int kt = 0; kt < Kd; kt += 32) {
    __syncthreads();
#pragma unroll
    for (int c = 0; c < 2; ++c) {
      const int rb = (c * 4 + w) * 16;
      const int64_t goff = (int64_t)(rb + srow) * Kd + kt + sk;
      gload16(Ah + (int64_t)m0 * Kd + goff, As + rb * 32);
      gload16(Wh + (int64_t)n0 * Kd + goff, Bs + rb * 32);
      if (SPLIT) {
        gload16(Al + (int64_t)m0 * Kd + goff, As + PL + rb * 32);
        gload16(Wl + (int64_t)n0 * Kd + goff, Bs + PL + rb * 32);
      }
    }
    __syncthreads();

    v8y afh[4], bfh[4], afl[4], bfl[4];
#pragma unroll
    for (int i = 0; i < 4; ++i) {
      const int ro = (wm + i * 16 + lr) * 32 + quad * 8;
      const int co = (wn + i * 16 + lr) * 32 + quad * 8;
      afh[i] = *reinterpret_cast<const v8y*>(As + ro);
      bfh[i] = *reinterpret_cast<const v8y*>(Bs + co);
      if (SPLIT) {
        afl[i] = *reinterpret_cast<const v8y*>(As + PL + ro);
        bfl[i] = *reinterpret_cast<const v8y*>(Bs + PL + co);
      }
    }
#pragma unroll
    for (int i = 0; i < 4; ++i)
#pragma unroll
      for (int j = 0; j < 4; ++j) {
        acc[i][j] = __builtin_amdgcn_mfma_f32_16x16x32_bf16(afh[i], bfh[j], acc[i][j], 0, 0, 0);
        if (SPLIT) {
          acc[i][j] = __builtin_amdgcn_mfma_f32_16x16x32_bf16(afh[i], bfl[j], acc[i][j], 0, 0, 0);
          acc[i][j] = __builtin_amdgcn_mfma_f32_16x16x32_bf16(afl[i], bfh[j], acc[i][j], 0, 0, 0);
        }
      }
  }

  // Epilogue: C/D layout col = lane&15, row = quad*4 + reg (m89-verified).
#pragma unroll
  for (int j = 0; j < 4; ++j) {
    const int gn = n0 + wn + j * 16 + lr;
    const float bv = bias[gn];
#pragma unroll
    for (int i = 0; i < 4; ++i) {
#pragma unroll
      for (int r = 0; r < 4; ++r) {
        const int gm = m0 + wm + i * 16 + quad * 4 + r;
        float v = acc[i][j][r] + bv;
        if (HEADLAYOUT) {
          const int bidx = gm >> 11, s = gm & (Sdim - 1);
          const int h = gn >> 6, hd = gn & (HD - 1);
          if (z == 0) v *= 0.125f;   // fold 1/sqrt(hd) into Q
          const int64_t idx = (z == 2)
            ? ((int64_t)(bidx * Hn + h) * HD + hd) * Sdim + s      // V transposed
            : (((int64_t)(bidx * Hn + h) * Sdim + s) << 6) + hd;   // Q/K natural
          stc(&C[idx], v);
        } else {
          stc(&C[(int64_t)gm * Nd + gn], v);
        }
      }
    }
  }
}

// MFMA flash attention, 64-key tiles. qh/kh in (b,h,s,hd); vt in (b,h,hd,s).
// One workgroup per (b*h, 64 q rows); wave w owns q rows q0..q0+15. Q pre-scaled.
// Key mask additive (softmax over key mask only; masked q rows zeroed at epilogue —
// matches reference nan_to_num semantics).
__global__ __launch_bounds__(256)
void attn_kernel(const bf* __restrict__ qh, const bf* __restrict__ kh,
                 const bf* __restrict__ vt, const int* __restrict__ mask,
                 bf* __restrict__ outp)
{
  __shared__ __align__(16) bf Kt[64 * 72];       // [key][hd], stride 72
  __shared__ __align__(16) bf Vt[64 * 72];       // [hd][key], stride 72
  __shared__ __align__(16) bf Pb[4][16 * 72];    // per-wave P, [q][key], stride 72

  const int tid = threadIdx.x;
  const int w = tid >> 6, l = tid & 63;
  const int bh = blockIdx.x;
  const int b = bh >> 4;
  const int q0 = blockIdx.y * 64 + w * 16;
  const int lr = l & 15, quad = l >> 4;
  const int64_t base = (int64_t)bh * Sdim * HD;

  v8y qf[2];
#pragma unroll
  for (int ks = 0; ks < 2; ++ks)
    qf[ks] = *reinterpret_cast<const v8y*>(qh + base + (q0 + lr) * 64 + ks * 32 + quad * 8);

  bool qm[4];
#pragma unroll
  for (int r = 0; r < 4; ++r) qm[r] = mask[b * Sdim + q0 + quad * 4 + r] != 0;

  float m_i[4], l_i[4];
#pragma unroll
  for (int r = 0; r < 4; ++r) { m_i[r] = NEG; l_i[r] = 0.f; }
  v4f O[4] = {};

  const int srow = tid >> 2, sc = (tid & 3) * 16;   // staging: 64 rows x 4 chunks of 16

  for (int kt = 0; kt < Sdim; kt += 64) {
    __syncthreads();
    {
      // K: [key][hd] — vectorized copy
      *reinterpret_cast<uint4*>(Kt + srow * 72 + sc) =
          *reinterpret_cast<const uint4*>(kh + base + (kt + srow) * 64 + sc);
      *reinterpret_cast<uint4*>(Kt + srow * 72 + sc + 8) =
          *reinterpret_cast<const uint4*>(kh + base + (kt + srow) * 64 + sc + 8);
      // V^T: [hd][key] — global already transposed, vectorized copy
      *reinterpret_cast<uint4*>(Vt + srow * 72 + sc) =
          *reinterpret_cast<const uint4*>(vt + base + (int64_t)srow * Sdim + kt + sc);
      *reinterpret_cast<uint4*>(Vt + srow * 72 + sc + 8) =
          *reinterpret_cast<const uint4*>(vt + base + (int64_t)srow * Sdim + kt + sc + 8);
    }
    __syncthreads();

    float addm[4];
#pragma unroll
    for (int nt = 0; nt < 4; ++nt)
      addm[nt] = mask[b * Sdim + kt + nt * 16 + lr] ? 0.f : NEG;

    // S = Q K^T : four 16-key tiles, two K-steps over hd
    v4f sf[4] = {};
#pragma unroll
    for (int nt = 0; nt < 4; ++nt)
#pragma unroll
      for (int ks = 0; ks < 2; ++ks) {
        v8y kf = *reinterpret_cast<const v8y*>(Kt + (nt * 16 + lr) * 72 + ks * 32 + quad * 8);
        sf[nt] = __builtin_amdgcn_mfma_f32_16x16x32_bf16(qf[ks], kf, sf[nt], 0, 0, 0);
      }

    float s[4][4];
#pragma unroll
    for (int nt = 0; nt < 4; ++nt)
#pragma unroll
      for (int r = 0; r < 4; ++r) s[nt][r] = sf[nt][r] + addm[nt];

    float mn[4], alpha[4], p[4][4];
#pragma unroll
    for (int r = 0; r < 4; ++r) {
      float v = fmaxf(fmaxf(s[0][r], s[1][r]), fmaxf(s[2][r], s[3][r]));
#pragma unroll
      for (int off = 1; off < 16; off <<= 1) v = fmaxf(v, __shfl_xor(v, off));
      mn[r] = fmaxf(m_i[r], v);
      alpha[r] = __expf(m_i[r] - mn[r]);
      m_i[r] = mn[r];
    }
#pragma unroll
    for (int r = 0; r < 4; ++r) {
      float sum = 0.f;
#pragma unroll
      for (int nt = 0; nt < 4; ++nt) { p[nt][r] = __expf(s[nt][r] - mn[r]); sum += p[nt][r]; }
#pragma unroll
      for (int off = 1; off < 16; off <<= 1) sum += __shfl_xor(sum, off);
      l_i[r] = l_i[r] * alpha[r] + sum;
    }
#pragma unroll
    for (int dt = 0; dt < 4; ++dt)
#pragma unroll
      for (int r = 0; r < 4; ++r) O[dt][r] *= alpha[r];

    // P: C-layout -> per-wave LDS -> A-layout (wave-private: lgkmcnt(0) suffices)
    bf* Pw = Pb[w];
#pragma unroll
    for (int nt = 0; nt < 4; ++nt)
#pragma unroll
      for (int r = 0; r < 4; ++r)
        Pw[(quad * 4 + r) * 72 + nt * 16 + lr] = __float2bfloat16(p[nt][r]);
    asm volatile("s_waitcnt lgkmcnt(0)" ::: "memory");

    v8y pa0 = *reinterpret_cast<const v8y*>(Pw + lr * 72 + quad * 8);
    v8y pa1 = *reinterpret_cast<const v8y*>(Pw + lr * 72 + 32 + quad * 8);
#pragma unroll
    for (int dt = 0; dt < 4; ++dt) {
      v8y vf0 = *reinterpret_cast<const v8y*>(Vt + (dt * 16 + lr) * 72 + quad * 8);
      O[dt] = __builtin_amdgcn_mfma_f32_16x16x32_bf16(pa0, vf0, O[dt], 0, 0, 0);
      v8y vf1 = *reinterpret_cast<const v8y*>(Vt + (dt * 16 + lr) * 72 + 32 + quad * 8);
      O[dt] = __builtin_amdgcn_mfma_f32_16x16x32_bf16(pa1, vf1, O[dt], 0, 0, 0);
    }
  }

#pragma unroll
  for (int dt = 0; dt < 4; ++dt)
#pragma unroll
    for (int r = 0; r < 4; ++r) {
      const int qrow = q0 + quad * 4 + r;
      const float v = qm[r] ? O[dt][r] / l_i[r] : 0.f;
      outp[((int64_t)b * Sdim + qrow) * Ddim + (bh & 15) * 64 + dt * 16 + lr] = __float2bfloat16(v);
    }
}

extern "C" void kernel_launch(void* const* d_in, const int* in_sizes, int n_in,
                              void* d_out, int out_size, void* d_ws, size_t ws_size,
                              hipStream_t stream) {
  (void)in_sizes; (void)n_in; (void)out_size; (void)ws_size;
  const float* q    = (const float*)d_in[0];
  const int*   mask = (const int*)d_in[1];   // int32 0/1 — verified round 7
  const float* Wq = (const float*)d_in[2];
  const float* bq = (const float*)d_in[3];
  const float* Wk = (const float*)d_in[4];
  const float* bk = (const float*)d_in[5];
  const float* Wv = (const float*)d_in[6];
  const float* bv = (const float*)d_in[7];
  const float* Wo = (const float*)d_in[8];
  const float* bo = (const float*)d_in[9];
  float* out = (float*)d_out;                // fp32 output — verified round 7
  bf* ws  = (bf*)d_ws;

  constexpr int SZ = Bb * Sdim * Ddim;   // 8,388,608

  bf* qc_h = ws;                 // A hi (reused as attention output `ao` later)
  bf* qc_l = ws + (size_t)SZ;    // A lo
  bf* qhp  = ws + 2 * (size_t)SZ;
  bf* khp  = ws + 3 * (size_t)SZ;
  bf* vtp  = ws + 4 * (size_t)SZ;    // V in (b,h,hd,s)
  bf* wb   = ws + 5 * (size_t)SZ;
  bf* wq_h = wb;            bf* wq_l = wb + WSZ;
  bf* wk_h = wb + 2 * WSZ;  bf* wk_l = wb + 3 * WSZ;
  bf* wv_h = wb + 4 * WSZ;  bf* wv_l = wb + 5 * WSZ;
  bf* wo_h = wb + 6 * WSZ;
  bf* ao   = qc_h;   // safe: QKV GEMM consumed qc before attn writes ao

  cvt_split<<<dim3(SZ / 2048), dim3(256), 0, stream>>>(q, qc_h, qc_l, SZ);
  cvt_w<<<dim3(WSZ / 2048, 4), dim3(256), 0, stream>>>(Wq, Wk, Wv, Wo, wb);

  // Fused QKV projections (split precision) -> Q scaled (b,h,s,hd), K (b,h,s,hd), V^T (b,h,hd,s)
  gemm_bt<true, true, bf><<<dim3(64, 8, 3), dim3(256), 0, stream>>>(
      qc_h, qc_l, wq_h, wq_l, wk_h, wk_l, wv_h, wv_l, bq, bk, bv, qhp, khp, vtp);

  // Attention -> (b,s,d) bf16
  attn_kernel<<<dim3(Bb * Hn, Sdim / 64), dim3(256), 0, stream>>>(qhp, khp, vtp, mask, ao);

  // Output projection (single bf16) -> d_out fp32
  gemm_bt<false, false, float><<<dim3(64, 8, 1), dim3(256), 0, stream>>>(
      ao, nullptr, wo_h, nullptr, wo_h, nullptr, wo_h, nullptr, bo, bo, bo, out, out, out);
}